// Round 11
// baseline (602.707 us; speedup 1.0000x reference)
//
#include <hip/hip_runtime.h>
#include <hip/hip_fp16.h>
#include <math.h>

#define F_IN 512
#define HD 64
#define CD 16
#define K_HOPS 10

#define BKT_SHIFT 7
#define BKT_NODES 128
#define NBKT_MAX 1024
#define EPB 8192

#define HOP_BLOCKS 2048

typedef unsigned int uint32;
typedef __attribute__((ext_vector_type(8))) short short8v;
typedef __attribute__((ext_vector_type(8))) unsigned short ushort8v;
typedef __attribute__((ext_vector_type(4))) float float4v;
typedef __attribute__((ext_vector_type(2))) float float2v;
typedef __attribute__((ext_vector_type(2))) unsigned int uint2v;

static __device__ __forceinline__ float bf2f(unsigned short h) {
    return __uint_as_float(((uint32)h) << 16);
}
static __device__ __forceinline__ unsigned short f2bf(float x) {
    uint32 u = __float_as_uint(x);
    u = (u + 0x7FFFu + ((u >> 16) & 1u)) >> 16;   // RNE
    return (unsigned short)u;
}

// fp8 e4m3 (OCP on gfx950) helpers
static __device__ __forceinline__ void fp8x8_acc(uint2v v, float* a) {
    float2v f;
    f = __builtin_amdgcn_cvt_pk_f32_fp8(v[0], false); a[0] += f[0]; a[1] += f[1];
    f = __builtin_amdgcn_cvt_pk_f32_fp8(v[0], true);  a[2] += f[0]; a[3] += f[1];
    f = __builtin_amdgcn_cvt_pk_f32_fp8(v[1], false); a[4] += f[0]; a[5] += f[1];
    f = __builtin_amdgcn_cvt_pk_f32_fp8(v[1], true);  a[6] += f[0]; a[7] += f[1];
}
static __device__ __forceinline__ unsigned int fp8pk4(float a, float b, float c, float d) {
    unsigned int u = (unsigned int)__builtin_amdgcn_cvt_pk_fp8_f32(a, b, 0, false);
    u = (unsigned int)__builtin_amdgcn_cvt_pk_fp8_f32(c, d, (int)u, true);
    return u;
}
static __device__ __forceinline__ unsigned char fp8one(float v) {
    return (unsigned char)((unsigned int)__builtin_amdgcn_cvt_pk_fp8_f32(v, v, 0, false) & 0xFFu);
}

// ---------------- CSR build: two-level bucket sort ----------------

__global__ void zero_kernel(int* __restrict__ p, int n) {
    int i = blockIdx.x * blockDim.x + threadIdx.x;
    if (i < n) p[i] = 0;
}

__global__ __launch_bounds__(256) void bucket_hist_kernel(
    const int* __restrict__ cols, int* __restrict__ bcnt, int e, int nb) {
    __shared__ int c[NBKT_MAX];
    int t = threadIdx.x;
    for (int i = t; i < nb; i += 256) c[i] = 0;
    __syncthreads();
    int base = blockIdx.x * EPB;
    int end = min(base + EPB, e);
    for (int i = base + t; i < end; i += 256)
        atomicAdd(&c[cols[i] >> BKT_SHIFT], 1);
    __syncthreads();
    for (int i = t; i < nb; i += 256)
        if (c[i]) atomicAdd(&bcnt[i], c[i]);
}

__global__ __launch_bounds__(256) void bucket_scan_kernel(
    const int* __restrict__ bcnt, int* __restrict__ bstart,
    int* __restrict__ bcur, int nb) {
    __shared__ int s[256];
    int t = threadIdx.x;
    int v[4]; int sum = 0;
#pragma unroll
    for (int i = 0; i < 4; ++i) {
        int idx = t * 4 + i;
        v[i] = (idx < nb) ? bcnt[idx] : 0;
        sum += v[i];
    }
    s[t] = sum; __syncthreads();
    for (int off = 1; off < 256; off <<= 1) {
        int x = (t >= off) ? s[t - off] : 0;
        __syncthreads();
        s[t] += x;
        __syncthreads();
    }
    int excl = s[t] - sum;
#pragma unroll
    for (int i = 0; i < 4; ++i) {
        int idx = t * 4 + i;
        if (idx < nb) { bstart[idx] = excl; bcur[idx] = excl; }
        excl += v[i];
    }
    if (t == 255) bstart[nb] = excl;
}

__global__ __launch_bounds__(256) void scatter_bin_kernel(
    const int* __restrict__ rows, const int* __restrict__ cols,
    int* __restrict__ bcur, uint32* __restrict__ stage, int e, int nb) {
    __shared__ int c[NBKT_MAX];
    int t = threadIdx.x;
    for (int i = t; i < nb; i += 256) c[i] = 0;
    __syncthreads();
    int base = blockIdx.x * EPB;
    int end = min(base + EPB, e);
    for (int i = base + t; i < end; i += 256)
        atomicAdd(&c[cols[i] >> BKT_SHIFT], 1);
    __syncthreads();
    for (int i = t; i < nb; i += 256) {
        int cc = c[i];
        if (cc) c[i] = atomicAdd(&bcur[i], cc);
    }
    __syncthreads();
    for (int i = base + t; i < end; i += 256) {
        int col = cols[i];
        int b = col >> BKT_SHIFT;
        int pos = atomicAdd(&c[b], 1);
        stage[pos] = ((uint32)rows[i] << BKT_SHIFT) | (uint32)(col & (BKT_NODES - 1));
    }
}

__global__ __launch_bounds__(256) void bucket_sort_kernel(
    const uint32* __restrict__ stage, const int* __restrict__ bstart,
    int* __restrict__ rowstart, float* __restrict__ dis,
    int* __restrict__ csr, int n, int e) {
    __shared__ int cnt[BKT_NODES];
    __shared__ int excl[BKT_NODES];
    __shared__ int lcur[BKT_NODES];
    int b = blockIdx.x, t = threadIdx.x;
    int s0 = bstart[b], s1 = bstart[b + 1];
    int nnode = min(BKT_NODES, n - b * BKT_NODES);
    if (t < BKT_NODES) cnt[t] = 0;
    __syncthreads();
    for (int i = s0 + t; i < s1; i += 256)
        atomicAdd(&cnt[stage[i] & (BKT_NODES - 1)], 1);
    __syncthreads();
    if (t < BKT_NODES) excl[t] = cnt[t];
    __syncthreads();
    for (int off = 1; off < BKT_NODES; off <<= 1) {
        int x = 0;
        if (t < BKT_NODES && t >= off) x = excl[t - off];
        __syncthreads();
        if (t < BKT_NODES) excl[t] += x;
        __syncthreads();
    }
    if (t < BKT_NODES) {
        int rs = s0 + excl[t] - cnt[t];
        lcur[t] = rs;
        if (t < nnode) {
            rowstart[b * BKT_NODES + t] = rs;
            dis[b * BKT_NODES + t] = rsqrtf((float)(cnt[t] + 1));
        }
    }
    if (b == 0 && t == 0) rowstart[n] = e;
    __syncthreads();
    for (int i = s0 + t; i < s1; i += 256) {
        uint32 v = stage[i];
        int pos = atomicAdd(&lcur[v & (BKT_NODES - 1)], 1);
        csr[pos] = (int)(v >> BKT_SHIFT);
    }
}

// ---------------- weight transpose + bf16 convert (one-time) -------------

__global__ void convw_kernel(const float* __restrict__ W1,
                             const float* __restrict__ W2,
                             unsigned short* __restrict__ w1t,
                             unsigned short* __restrict__ w2t) {
    int i = blockIdx.x * blockDim.x + threadIdx.x;
    if (i < HD * F_IN) {
        int h = i >> 9, k = i & 511;
        w1t[i] = f2bf(W1[k * HD + h]);
    } else {
        int j = i - HD * F_IN;
        if (j < CD * HD) {
            int c = j >> 6, k = j & 63;
            w2t[j] = f2bf(W2[k * CD + c]);
        }
    }
}

// ---------------- MFMA MLP + riemann + init ------------------------------

#define LSTR 72

__global__ __launch_bounds__(256) void mlp_kernel(
    const float* __restrict__ x, const unsigned short* __restrict__ w1t,
    const float* __restrict__ b1, const unsigned short* __restrict__ w2t,
    const float* __restrict__ b2, const float* __restrict__ dis,
    const float* __restrict__ temp, const float* __restrict__ wfn,
    unsigned char* __restrict__ g0, float* __restrict__ hidden, int n) {
    __shared__ __align__(16) unsigned short xb[64 * LSTR];
    __shared__ __align__(16) unsigned short w1b[64 * LSTR];
    __shared__ __align__(16) unsigned short w2b[16 * LSTR];

    const int t = threadIdx.x;
    const int row0 = blockIdx.x * 64;
    const int wave = t >> 6, lane = t & 63;
    const int l15 = lane & 15, lq = lane >> 4;
    const int lrow = (wave << 4) + l15;

    if (t < 128) {
        int cr = t >> 3, part = t & 7;
        *(short8v*)&w2b[cr * LSTR + part * 8] =
            *(const short8v*)&w2t[cr * HD + part * 8];
    }

    float4v acc[4];
#pragma unroll
    for (int i = 0; i < 4; ++i) acc[i] = (float4v)0.0f;

    const int srow = t >> 2, spart = t & 3;
    for (int c = 0; c < F_IN / 64; ++c) {
        __syncthreads();
        {
            int gr = row0 + srow; if (gr >= n) gr = n - 1;
            const float* xp = x + (long)gr * F_IN + c * 64 + spart * 16;
            float4 v0 = *(const float4*)(xp + 0);
            float4 v1 = *(const float4*)(xp + 4);
            float4 v2 = *(const float4*)(xp + 8);
            float4 v3 = *(const float4*)(xp + 12);
            short8v o0, o1;
            o0[0] = (short)f2bf(v0.x); o0[1] = (short)f2bf(v0.y);
            o0[2] = (short)f2bf(v0.z); o0[3] = (short)f2bf(v0.w);
            o0[4] = (short)f2bf(v1.x); o0[5] = (short)f2bf(v1.y);
            o0[6] = (short)f2bf(v1.z); o0[7] = (short)f2bf(v1.w);
            o1[0] = (short)f2bf(v2.x); o1[1] = (short)f2bf(v2.y);
            o1[2] = (short)f2bf(v2.z); o1[3] = (short)f2bf(v2.w);
            o1[4] = (short)f2bf(v3.x); o1[5] = (short)f2bf(v3.y);
            o1[6] = (short)f2bf(v3.z); o1[7] = (short)f2bf(v3.w);
            *(short8v*)&xb[srow * LSTR + spart * 16] = o0;
            *(short8v*)&xb[srow * LSTR + spart * 16 + 8] = o1;
            const unsigned short* wp = w1t + srow * F_IN + c * 64 + spart * 16;
            *(short8v*)&w1b[srow * LSTR + spart * 16] = *(const short8v*)(wp);
            *(short8v*)&w1b[srow * LSTR + spart * 16 + 8] = *(const short8v*)(wp + 8);
        }
        __syncthreads();
#pragma unroll
        for (int st = 0; st < 2; ++st) {
            int kb = st * 32 + lq * 8;
            short8v av = *(const short8v*)&xb[lrow * LSTR + kb];
#pragma unroll
            for (int hf = 0; hf < 4; ++hf) {
                short8v bv = *(const short8v*)&w1b[(hf * 16 + l15) * LSTR + kb];
                acc[hf] = __builtin_amdgcn_mfma_f32_16x16x32_bf16(av, bv, acc[hf], 0, 0, 0);
            }
        }
    }

    __syncthreads();
    {
        int drow = (wave << 4) + (lq << 2);
#pragma unroll
        for (int hf = 0; hf < 4; ++hf) {
            int h = hf * 16 + l15;
            float bv = b1[h];
#pragma unroll
            for (int i = 0; i < 4; ++i) {
                float v = acc[hf][i] + bv;
                v = v > 0.0f ? v : 0.0f;
                xb[(drow + i) * LSTR + h] = f2bf(v);
            }
        }
    }
    __syncthreads();

    float4v acc2 = (float4v)0.0f;
#pragma unroll
    for (int st = 0; st < 2; ++st) {
        int kb = st * 32 + lq * 8;
        short8v av = *(const short8v*)&xb[lrow * LSTR + kb];
        short8v bv = *(const short8v*)&w2b[l15 * LSTR + kb];
        acc2 = __builtin_amdgcn_mfma_f32_16x16x32_bf16(av, bv, acc2, 0, 0, 0);
    }

    {
        const int cc = l15;
        const int drow = (wave << 4) + (lq << 2);
        float b2c = b2[cc];
        float wabs = fabsf(wfn[cc]);
        float o[4], p[4];
#pragma unroll
        for (int i = 0; i < 4; ++i) {
            o[i] = acc2[i] + b2c;
            p[i] = o[i] * o[i] * wabs;
        }
#pragma unroll
        for (int off = 1; off < 16; off <<= 1) {
#pragma unroll
            for (int i = 0; i < 4; ++i) p[i] += __shfl_xor(p[i], off);
        }
        float t0 = temp[0];
#pragma unroll
        for (int i = 0; i < 4; ++i) {
            int grow = row0 + drow + i;
            if (grow < n) {
                float inv = 1.0f / (sqrtf(p[i] + 0.01f) + 0.01f);
                float hn = o[i] * inv;
                float d = dis[grow];
                hidden[(long)grow * CD + cc] = t0 * hn;
                g0[(long)grow * CD + cc] = fp8one(d * hn);
            }
        }
    }
}

// ---------------- fused hop: fp8 g L2-resident; everything else streams --
// wave/node, 32 slots x 2 half-rows; csr via nontemporal loads; hidden
// REMOVED from hop (hn_k written bf16 nt, accumulated in one final pass).

__global__ __launch_bounds__(256) void hop_kernel(
    const unsigned char* __restrict__ g, unsigned char* __restrict__ gn,
    unsigned short* __restrict__ hnk, const float* __restrict__ dis,
    const int* __restrict__ rowstart, const int* __restrict__ csr,
    const float* __restrict__ wfn, int writeg, int n, int etot) {
    const int wv = (blockIdx.x << 2) + (threadIdx.x >> 6);
    const int NW = gridDim.x << 2;
    if (wv >= n) return;
    const int lane = threadIdx.x & 63;
    const int slot = lane >> 1, fl = lane & 1;   // 32 slots x 2 half-rows

    float w8[8];
#pragma unroll
    for (int j = 0; j < 8; ++j) w8[j] = fabsf(wfn[(fl << 3) + j]);

    // prologue: first node
    int node = wv;
    int rs0 = rowstart[node], rs1 = rowstart[node + 1];
    float d = dis[node];
    uint2v sv = *(const uint2v*)(g + ((long)node << 4) + (fl << 3));
    int c0 = __builtin_nontemporal_load(&csr[min(rs0 + slot, etot - 1)]);

    for (;;) {
        const int nnext = node + NW;
        const bool has_next = nnext < n;

        // (1) next node's independent loads
        int rs0n, rs1n; float dn; uint2v svn;
        if (has_next) {
            rs0n = rowstart[nnext];
            rs1n = rowstart[nnext + 1];
            dn = dis[nnext];
            svn = *(const uint2v*)(g + ((long)nnext << 4) + (fl << 3));
        }

        // (2) gather: 32 edges/round, 8B fp8 per lane (L2-resident g)
        float a[8];
#pragma unroll
        for (int j = 0; j < 8; ++j) a[j] = 0.0f;
        if (rs0 + slot < rs1) {
            uint2v v = *(const uint2v*)(g + ((long)c0 << 4) + (fl << 3));
            fp8x8_acc(v, a);
        }
        for (int e2 = rs0 + slot + 32; e2 < rs1; e2 += 32) {
            int s1 = __builtin_nontemporal_load(&csr[e2]);
            uint2v v = *(const uint2v*)(g + ((long)s1 << 4) + (fl << 3));
            fp8x8_acc(v, a);
        }

        // (3) butterfly over 32 slots, packed f16x2
        {
            unsigned int pk[4];
#pragma unroll
            for (int i = 0; i < 4; ++i) {
                __half2 hh = __floats2half2_rn(a[2 * i], a[2 * i + 1]);
                pk[i] = *(unsigned int*)&hh;
            }
#pragma unroll
            for (int off = 2; off < 64; off <<= 1) {
#pragma unroll
                for (int i = 0; i < 4; ++i) {
                    unsigned int o = (unsigned int)__shfl_xor((int)pk[i], off);
                    __half2 s = *(__half2*)&pk[i] + *(__half2*)&o;
                    pk[i] = *(unsigned int*)&s;
                }
            }
#pragma unroll
            for (int i = 0; i < 4; ++i) {
                float2 f = __half22float2(*(__half2*)&pk[i]);
                a[2 * i] = f.x;
                a[2 * i + 1] = f.y;
            }
        }

        // (4) self-loop + dis scale + riemann
        {
            float s8[8];
#pragma unroll
            for (int j = 0; j < 8; ++j) s8[j] = 0.0f;
            fp8x8_acc(sv, s8);
#pragma unroll
            for (int j = 0; j < 8; ++j) a[j] = (a[j] + s8[j]) * d;
        }
        float p = 0.0f;
#pragma unroll
        for (int j = 0; j < 8; ++j) p += a[j] * a[j] * w8[j];
        p += __shfl_xor(p, 1);
        float inv = 1.0f / (sqrtf(p + 0.01f) + 0.01f);

        // (5) writes: hn (bf16, nt) always; gn (fp8, nt) if more hops
        if (slot == 0) {
            long base = ((long)node << 4) + (fl << 3);
            ushort8v hv;
#pragma unroll
            for (int j = 0; j < 8; ++j) hv[j] = f2bf(a[j] * inv);
            __builtin_nontemporal_store(hv, (ushort8v*)(hnk + base));
            if (writeg) {
                float di = d * inv;
                uint2v o;
                o[0] = fp8pk4(di * a[0], di * a[1], di * a[2], di * a[3]);
                o[1] = fp8pk4(di * a[4], di * a[5], di * a[6], di * a[7]);
                __builtin_nontemporal_store(o, (uint2v*)(gn + base));
            }
        }

        if (!has_next) break;

        // (6) prefetch next node's first-round csr
        int c0n = __builtin_nontemporal_load(&csr[min(rs0n + slot, etot - 1)]);

        // (7) rotate
        node = nnext;
        rs0 = rs0n; rs1 = rs1n; d = dn; sv = svn; c0 = c0n;
    }
}

// ---------------- final: hidden += sum_k temp[k] * hn_k ------------------

__global__ __launch_bounds__(256) void final_kernel(
    const unsigned short* __restrict__ hn_all, const float* __restrict__ temp,
    float* __restrict__ hidden, int n) {
    int t = blockIdx.x * blockDim.x + threadIdx.x;
    int node = t >> 1, fl = t & 1;
    if (node >= n) return;
    long base = ((long)node << 4) + (fl << 3);
    float4 h0 = *(const float4*)(hidden + base);
    float4 h1 = *(const float4*)(hidden + base + 4);
    const long stride = (long)n << 4;
#pragma unroll
    for (int k = 0; k < K_HOPS; ++k) {
        float tk = temp[k + 1];
        ushort8v v = *(const ushort8v*)(hn_all + (long)k * stride + base);
        h0.x = fmaf(tk, bf2f(v[0]), h0.x);
        h0.y = fmaf(tk, bf2f(v[1]), h0.y);
        h0.z = fmaf(tk, bf2f(v[2]), h0.z);
        h0.w = fmaf(tk, bf2f(v[3]), h0.w);
        h1.x = fmaf(tk, bf2f(v[4]), h1.x);
        h1.y = fmaf(tk, bf2f(v[5]), h1.y);
        h1.z = fmaf(tk, bf2f(v[6]), h1.z);
        h1.w = fmaf(tk, bf2f(v[7]), h1.w);
    }
    *(float4*)(hidden + base) = h0;
    *(float4*)(hidden + base + 4) = h1;
}

// ---------------- launch ----------------

static inline long align4up(long w) { return (w + 3) & ~3L; }

extern "C" void kernel_launch(void* const* d_in, const int* in_sizes, int n_in,
                              void* d_out, int out_size, void* d_ws, size_t ws_size,
                              hipStream_t stream) {
    const float* x          = (const float*)d_in[0];
    const int*   edge_index = (const int*)d_in[1];
    const float* W1         = (const float*)d_in[2];
    const float* b1         = (const float*)d_in[3];
    const float* W2         = (const float*)d_in[4];
    const float* b2         = (const float*)d_in[5];
    const float* temp       = (const float*)d_in[6];
    const float* w_for_norm = (const float*)d_in[7];
    float* hidden = (float*)d_out;

    const int n = in_sizes[0] / F_IN;
    const int e = in_sizes[1] / 2;
    const int* rows = edge_index;        // sources
    const int* cols = edge_index + e;    // destinations
    const int nb = (n + BKT_NODES - 1) / BKT_NODES;

    long off = 0;
    int* wsI = (int*)d_ws;
    int* bcnt      = wsI + off; off = align4up(off + NBKT_MAX);
    int* bstart    = wsI + off; off = align4up(off + NBKT_MAX + 1);
    int* bcur      = wsI + off; off = align4up(off + NBKT_MAX);
    int* rowstart  = wsI + off; off = align4up(off + n + 1);
    float* dis     = (float*)(wsI + off); off = align4up(off + n);
    uint32* stage  = (uint32*)(wsI + off); off = align4up(off + e);
    int* csr       = wsI + off; off = align4up(off + e);
    unsigned short* w1t = (unsigned short*)(wsI + off); off = align4up(off + HD * F_IN / 2);
    unsigned short* w2t = (unsigned short*)(wsI + off); off = align4up(off + CD * HD / 2);
    unsigned char* gA = (unsigned char*)(wsI + off); off = align4up(off + n * 4);
    unsigned char* gB = (unsigned char*)(wsI + off); off = align4up(off + n * 4);
    unsigned short* hn_all = (unsigned short*)(wsI + off);
    off = align4up(off + (long)K_HOPS * n * 8);

    const int B = 256;
    const int nbC = (e + EPB - 1) / EPB;

    zero_kernel<<<(nb + B - 1) / B, B, 0, stream>>>(bcnt, nb);
    bucket_hist_kernel<<<nbC, B, 0, stream>>>(cols, bcnt, e, nb);
    bucket_scan_kernel<<<1, B, 0, stream>>>(bcnt, bstart, bcur, nb);
    scatter_bin_kernel<<<nbC, B, 0, stream>>>(rows, cols, bcur, stage, e, nb);
    bucket_sort_kernel<<<nb, B, 0, stream>>>(stage, bstart, rowstart, dis, csr, n, e);
    convw_kernel<<<(HD * F_IN + CD * HD + B - 1) / B, B, 0, stream>>>(W1, W2, w1t, w2t);

    mlp_kernel<<<(n + 63) / 64, B, 0, stream>>>(x, w1t, b1, w2t, b2, dis, temp,
                                                w_for_norm, gA, hidden, n);

    unsigned char* gsrc = gA;
    unsigned char* gdst = gB;
    for (int k = 1; k <= K_HOPS; ++k) {
        hop_kernel<<<HOP_BLOCKS, B, 0, stream>>>(
            gsrc, gdst, hn_all + (long)(k - 1) * n * CD, dis, rowstart, csr,
            w_for_norm, (k < K_HOPS) ? 1 : 0, n, e);
        unsigned char* tmp = gsrc; gsrc = gdst; gdst = tmp;
    }

    final_kernel<<<(2 * n + B - 1) / B, B, 0, stream>>>(hn_all, temp, hidden, n);
}